// Round 11
// baseline (307.402 us; speedup 1.0000x reference)
//
#include <hip/hip_runtime.h>
#include <hip/hip_bf16.h>
#include <hip/hip_fp16.h>

typedef float v2f __attribute__((ext_vector_type(2)));

// ---------------- problem constants ----------------
#define B_    4
#define C_    4
#define Q_    8
#define J_    5
#define T_    15
#define NSIG  65536
#define N2SIG 32768
#define NOUT  16384
#define NCH   (B_ * C_)

// ---------------- wavelet filters ----------------
constexpr float H0Oc[13] = {
    -0.00455690456024f, -0.00543947593727f,  0.01702522388155f,  0.02382538479492f,
    -0.10671180468666f,  0.01186609203379f,  0.56881042071212f,  0.75614564389252f,
     0.27529538466888f, -0.11720388769911f, -0.03887280126882f,  0.03466034684485f,
    -0.00388321199915f };
constexpr float H1Oc[13] = {
    -0.00388321199915f, -0.03466034684485f, -0.03887280126882f,  0.11720388769911f,
     0.27529538466888f, -0.75614564389252f,  0.56881042071212f, -0.01186609203379f,
    -0.10671180468666f, -0.02382538479492f,  0.01702522388155f,  0.00543947593727f,
    -0.00455690456024f };
constexpr float H0Ac[10] = {
     0.03516384f, 0.0f, -0.08832942f, 0.23389032f, 0.76027237f,
     0.58751830f, 0.0f, -0.11430184f, 0.0f, 0.0f };
constexpr float H0Bc[10] = {
     0.0f, 0.0f, -0.11430184f, 0.0f, 0.58751830f,
     0.76027237f, 0.23389032f, -0.08832942f, 0.0f, 0.03516384f };
constexpr float H1Ac[10] = {
     0.0f, 0.0f, -0.11430184f, 0.0f, 0.58751830f,
    -0.76027237f, 0.23389032f, 0.08832942f, 0.0f, -0.03516384f };
constexpr float H1Bc[10] = {
    -0.03516384f, 0.0f, 0.08832942f, 0.23389032f, -0.76027237f,
     0.58751830f, 0.0f, -0.11430184f, 0.0f, 0.0f };

// fused two-stage lowpass+decimate: out[m] = sum_n g[n] * u[4m + n - 18]
struct Gtab { float v[37]; };
constexpr Gtab make_g() {
    Gtab g{};
    for (int n = 0; n < 37; ++n) {
        float s = 0.f;
        for (int k = 0; k < 13; ++k) {
            int l = n - 2 * k;
            if (l >= 0 && l < 13) s += H0Oc[k] * H0Oc[l];
        }
        g.v[n] = s;
    }
    return g;
}
constexpr Gtab cG = make_g();

// ---------------- tiling (r8/r10 structure: per-j grid, M2=256) -----------
// History: r10 = 112us/162 champion. Ledger (bytes @85B/cy/CU): block LDS
// ~880KB -> floor ~100us; measured 112 = ~90% of LDS-BW. This round removes
// BYTES: U planes stored as 4xf16 packed in uint2 (one elem per item holds
// q0..q3). ds-reads 303->151KB + instr halved; U-writes 34->17KB. sRI stays
// f32 (bandpass precision full). Accepted risk: absmax +~2e-3.
// Standing lessons: r1/r7 conflict "fixes" regress (conflicts absorbed);
// r3 VGPR cap < ~84 -> spill disaster (watch WRITE_SIZE); r5/r6 merged
// chain -> barrier convoy; r9 chain->ws split net-negative; g2 tap-merge
// blocked by SGPR wall (8x15 uniform weights don't fit).
#define M2    256
#define NUcnt 1057               // 4*(M2-1) + 37
#define NUP   1064               // U plane stride (uint2 elems)
#define NBcnt 1169
#define NBP   1176
#define S_    1320               // x window (halo 73 left / 74 right)

#define SMEM_FLOATS (5280 + 2 * NBP)   // 7632 floats = 30528 B (unchanged)

__device__ __forceinline__ v2f zmask(v2f a, bool ok) {
    if (!ok) { a.x = 0.f; a.y = 0.f; }
    return a;
}

// ---- 4xf16 pack/unpack for U plane (q0,q1 | q2,q3 in one uint2) ---------
__device__ __forceinline__ uint2 pack4h(float a, float b, float c, float d) {
    float2 f01; f01.x = a; f01.y = b;
    float2 f23; f23.x = c; f23.y = d;
    __half2 h01 = __float22half2_rn(f01);
    __half2 h23 = __float22half2_rn(f23);
    uint2 r;
    r.x = *reinterpret_cast<unsigned*>(&h01);
    r.y = *reinterpret_cast<unsigned*>(&h23);
    return r;
}
__device__ __forceinline__ void unpack4h(uint2 pk, v2f& v01, v2f& v23) {
    __half2 h01 = *reinterpret_cast<__half2*>(&pk.x);
    __half2 h23 = *reinterpret_cast<__half2*>(&pk.y);
    float2 f01 = __half22float2(h01);
    float2 f23 = __half22float2(h23);
    v01.x = f01.x; v01.y = f01.y;
    v23.x = f23.x; v23.y = f23.y;
}

// ---------------- post stage (u + fused downsample) ----------------------
template<int D, bool EDGE>
__device__ __forceinline__ void post_stage(
        const v2f* __restrict__ sRI, uint2* __restrict__ Upk,
        const float* __restrict__ cw, const float* __restrict__ roots,
        float beta, int j, int b, int c, int m0, int mt, int tid,
        float* __restrict__ out) {
    const float lg_is = -0.5f * (float)j;                // log2(inv_scale)
    const float beta2 = beta * exp2f(0.5f * (float)j);   // beta * scale
    const int   u_lo  = 4 * m0 - 18;

    for (int g2 = 0; g2 < 2; ++g2) {
        // uniform weights / alphas (wave-uniform addresses -> SGPRs)
        float w[4][T_], al[4], cq[4];
        #pragma unroll
        for (int qq = 0; qq < 4; ++qq) {
            const int o = c * Q_ + g2 * 4 + qq;
            #pragma unroll
            for (int t = 0; t < T_; t++) w[qq][t] = cw[(size_t)(j * 32 + o) * T_ + t];
            al[qq] = 1.f / (1.f + __expf(-roots[j * 32 + o]));
            cq[qq] = al[qq] * lg_is;
        }

        if constexpr (D == 1) {
            // contiguous-5 u-stage: one 19-v2f window serves 5 items (r10)
            const int i0 = 5 * tid;
            if (i0 < NUcnt) {
                v2f win[19];
                const v2f* tp = sRI + (i0 + 49);   // i + 56 - 7*1
                #pragma unroll
                for (int s = 0; s < 19; ++s) win[s] = tp[s];
                #pragma unroll
                for (int d = 0; d < 5; ++d) {
                    if (i0 + d >= NUcnt) continue;
                    bool ok = true;
                    if constexpr (EDGE)
                        ok = ((unsigned)(u_lo + i0 + d) < (unsigned)NSIG);
                    float uq[4];
                    #pragma unroll
                    for (int qq = 0; qq < 4; ++qq) {
                        v2f ri; ri.x = 0.f; ri.y = 0.f;
                        #pragma unroll
                        for (int t = 0; t < T_; t++) ri += w[qq][t] * win[d + t];
                        float z2 = fmaf(ri.x, ri.x, ri.y * ri.y);
                        float us = __builtin_amdgcn_sqrtf(z2);
                        float lg = __builtin_amdgcn_logf(us + beta2);
                        float u  = __builtin_amdgcn_exp2f(fmaf(al[qq], lg, cq[qq]));
                        if constexpr (EDGE) uq[qq] = ok ? u : 0.f;
                        else                uq[qq] = u;
                    }
                    Upk[i0 + d] = pack4h(uq[0], uq[1], uq[2], uq[3]);
                }
            }
        } else {
            // strided u-stage (proven form) for D >= 2
            for (int i = tid; i < NUcnt; i += 256) {
                const v2f* tp = sRI + (i + 56 - 7 * D);
                v2f taps[T_];
                #pragma unroll
                for (int t = 0; t < T_; t++) taps[t] = tp[t * D];
                bool ok = true;
                if constexpr (EDGE) {
                    const int n = u_lo + i;
                    ok = ((unsigned)n < (unsigned)NSIG);
                }
                float uq[4];
                #pragma unroll
                for (int qq = 0; qq < 4; ++qq) {
                    v2f ri; ri.x = 0.f; ri.y = 0.f;
                    #pragma unroll
                    for (int t = 0; t < T_; t++) ri += w[qq][t] * taps[t];
                    float z2 = fmaf(ri.x, ri.x, ri.y * ri.y);
                    float us = __builtin_amdgcn_sqrtf(z2);
                    float lg = __builtin_amdgcn_logf(us + beta2);
                    float u  = __builtin_amdgcn_exp2f(fmaf(al[qq], lg, cq[qq]));
                    if constexpr (EDGE) uq[qq] = ok ? u : 0.f;
                    else                uq[qq] = u;
                }
                Upk[i] = pack4h(uq[0], uq[1], uq[2], uq[3]);
            }
        }
        __syncthreads();

        // ---- fused 37-tap stride-4 downsample: ONE pass, all 4 q's ----
        // (uint2 read = half the ds instr+bytes of the old 2x b64 passes;
        //  same 16-way bank pattern as before — absorbed, do not "fix".)
        {
            const int m = m0 + tid;                 // tid < 256 always
            const uint2* ub = Upk + 4 * tid;
            v2f a01; a01.x = 0.f; a01.y = 0.f;
            v2f a23; a23.x = 0.f; a23.y = 0.f;
            #pragma unroll
            for (int n = 0; n < 37; ++n) {
                v2f v01, v23;
                unpack4h(ub[n], v01, v23);
                a01 += cG.v[n] * v01;
                a23 += cG.v[n] * v23;
            }
            if constexpr (EDGE) {
                const bool edge = (mt == 0 && tid < 3) || (mt == 63 && tid >= 253);
                if (edge) {
                    // exact two-stage computation honoring v-plane masking
                    v2f b01; b01.x = 0.f; b01.y = 0.f;
                    v2f b23; b23.x = 0.f; b23.y = 0.f;
                    for (int k = 0; k < 13; ++k) {
                        int p = 2 * m + k - 6;
                        if (p < 0 || p >= N2SIG) continue;
                        v2f s01; s01.x = 0.f; s01.y = 0.f;
                        v2f s23; s23.x = 0.f; s23.y = 0.f;
                        for (int l = 0; l < 13; ++l) {
                            v2f v01, v23;
                            unpack4h(Upk[4 * tid + 2 * k + l], v01, v23);
                            s01 += H0Oc[l] * v01;
                            s23 += H0Oc[l] * v23;
                        }
                        b01 += H0Oc[k] * s01;
                        b23 += H0Oc[k] * s23;
                    }
                    a01 = b01; a23 = b23;
                }
            }
            const int o = c * Q_ + g2 * 4;
            out[((size_t)b * 160 + j * 32 + o)     * NOUT + m] = a01.x;
            out[((size_t)b * 160 + j * 32 + o + 1) * NOUT + m] = a01.y;
            out[((size_t)b * 160 + j * 32 + o + 2) * NOUT + m] = a23.x;
            out[((size_t)b * 160 + j * 32 + o + 3) * NOUT + m] = a23.y;
        }
        __syncthreads();   // protect U plane before next group's writes
    }
}

// ---------------- whole tile, templated on block-uniform EDGE ------------
template<bool EDGE>
__device__ __forceinline__ void run_tile(
        float* __restrict__ smem,
        const float* __restrict__ x, const float* __restrict__ cw,
        const float* __restrict__ roots, float beta,
        float* __restrict__ out, int j, int mt, int ch, int tid) {
    float* X   = smem;                       // [0,1320)
    float* L1  = smem + S_;                  // [1320,2640)
    v2f*   PP0 = (v2f*)smem;                 // aliases X/L1 (used after dead)
    v2f*   PP1 = (v2f*)(smem + 2 * S_);      // floats [2640,5280)
    uint2* Upk = (uint2*)smem;               // aliases chain region (dead then)
    v2f*   sRI = (v2f*)(smem + 4 * S_);      // floats [5280,7632)

    const int b   = ch >> 2, c = ch & 3;
    const int m0  = mt * M2;
    const int ofs = 4 * m0 - 147;            // window start (bp index 0 at p=73)
    const float* xc = x + (size_t)ch * NSIG;

    // ---- load x window ----
    for (int p = tid; p < S_; p += 256) {
        if constexpr (EDGE) {
            int g = ofs + p;
            X[p] = ((unsigned)g < (unsigned)NSIG) ? xc[g] : 0.f;
        } else {
            X[p] = xc[ofs + p];
        }
    }
    __syncthreads();

    // ---- UDTCWT chain (branches block-uniform in j) ----
    if (j == 0) {
        for (int i = tid; i < NBcnt; i += 256) {
            int p = 73 + i;
            float a = 0.f;
            #pragma unroll
            for (int k = 0; k < 13; k++) a += H1Oc[k] * X[p + k - 6];
            if constexpr (EDGE) { if ((unsigned)(ofs + p) >= (unsigned)NSIG) a = 0.f; }
            v2f r; r.x = a; r.y = a;
            sRI[i] = r;
        }
    } else {
        // lv0: la1 = conv13(x, H0O) -> L1
        for (int p = 6 + tid; p < 1313; p += 256) {
            float a = 0.f;
            #pragma unroll
            for (int k = 0; k < 13; k++) a += H0Oc[k] * X[p + k - 6];
            if constexpr (EDGE) { if ((unsigned)(ofs + p) >= (unsigned)NSIG) a = 0.f; }
            L1[p] = a;
        }
        __syncthreads();
        if (j == 1) {
            for (int i = tid; i < NBcnt; i += 256) {
                int p = 73 + i;
                v2f r; r.x = 0.f; r.y = 0.f;
                #pragma unroll
                for (int k = 0; k < 10; k++) {
                    v2f hk; hk.x = H1Ac[k]; hk.y = H1Bc[k];
                    r += hk * L1[p + k - 4];
                }
                if constexpr (EDGE) r = zmask(r, (unsigned)(ofs + p) < (unsigned)NSIG);
                sRI[i] = r;
            }
        } else {
            // lv1 (d=1, pad 4): (la2,lb2) -> PP1
            for (int p = 10 + tid; p < 1308; p += 256) {
                v2f a; a.x = 0.f; a.y = 0.f;
                #pragma unroll
                for (int k = 0; k < 10; k++) {
                    v2f hk; hk.x = H0Ac[k]; hk.y = H0Bc[k];
                    a += hk * L1[p + k - 4];
                }
                if constexpr (EDGE) a = zmask(a, (unsigned)(ofs + p) < (unsigned)NSIG);
                PP1[p] = a;
            }
            __syncthreads();
            if (j == 2) {
                for (int i = tid; i < NBcnt; i += 256) {
                    int p = 73 + i;
                    v2f r; r.x = 0.f; r.y = 0.f;
                    #pragma unroll
                    for (int k = 0; k < 10; k++) {
                        v2f hk; hk.x = H1Ac[k]; hk.y = H1Bc[k];
                        r += hk * PP1[p + 2 * k - 9];
                    }
                    if constexpr (EDGE) r = zmask(r, (unsigned)(ofs + p) < (unsigned)NSIG);
                    sRI[i] = r;
                }
            } else {
                // lv2 (d=2, pad 9): (la3,lb3) -> PP0  (X/L1 dead)
                for (int p = 19 + tid; p < 1299; p += 256) {
                    v2f a; a.x = 0.f; a.y = 0.f;
                    #pragma unroll
                    for (int k = 0; k < 10; k++) {
                        v2f hk; hk.x = H0Ac[k]; hk.y = H0Bc[k];
                        a += hk * PP1[p + 2 * k - 9];
                    }
                    if constexpr (EDGE) a = zmask(a, (unsigned)(ofs + p) < (unsigned)NSIG);
                    PP0[p] = a;
                }
                __syncthreads();
                if (j == 3) {
                    for (int i = tid; i < NBcnt; i += 256) {
                        int p = 73 + i;
                        v2f r; r.x = 0.f; r.y = 0.f;
                        #pragma unroll
                        for (int k = 0; k < 10; k++) {
                            v2f hk; hk.x = H1Ac[k]; hk.y = H1Bc[k];
                            r += hk * PP0[p + 4 * k - 18];
                        }
                        if constexpr (EDGE) r = zmask(r, (unsigned)(ofs + p) < (unsigned)NSIG);
                        sRI[i] = r;
                    }
                } else {
                    // lv3 (d=4, pad 18): (la4,lb4) -> PP1 (old PP1 dead)
                    for (int p = 37 + tid; p < 1281; p += 256) {
                        v2f a; a.x = 0.f; a.y = 0.f;
                        #pragma unroll
                        for (int k = 0; k < 10; k++) {
                            v2f hk; hk.x = H0Ac[k]; hk.y = H0Bc[k];
                            a += hk * PP0[p + 4 * k - 18];
                        }
                        if constexpr (EDGE) a = zmask(a, (unsigned)(ofs + p) < (unsigned)NSIG);
                        PP1[p] = a;
                    }
                    __syncthreads();
                    // j == 4 bandpass (d=8, pad 36)
                    for (int i = tid; i < NBcnt; i += 256) {
                        int p = 73 + i;
                        v2f r; r.x = 0.f; r.y = 0.f;
                        #pragma unroll
                        for (int k = 0; k < 10; k++) {
                            v2f hk; hk.x = H1Ac[k]; hk.y = H1Bc[k];
                            r += hk * PP1[p + 8 * k - 36];
                        }
                        if constexpr (EDGE) r = zmask(r, (unsigned)(ofs + p) < (unsigned)NSIG);
                        sRI[i] = r;
                    }
                }
            }
        }
    }
    __syncthreads();
    // PP/X/L1 dead: region becomes the packed U plane.

    if (j == 0)      post_stage<1, EDGE>(sRI, Upk, cw, roots, beta, 0, b, c, m0, mt, tid, out);
    else if (j == 1) post_stage<1, EDGE>(sRI, Upk, cw, roots, beta, 1, b, c, m0, mt, tid, out);
    else if (j == 2) post_stage<2, EDGE>(sRI, Upk, cw, roots, beta, 2, b, c, m0, mt, tid, out);
    else if (j == 3) post_stage<4, EDGE>(sRI, Upk, cw, roots, beta, 3, b, c, m0, mt, tid, out);
    else             post_stage<8, EDGE>(sRI, Upk, cw, roots, beta, 4, b, c, m0, mt, tid, out);
}

// ---------------- fused kernel ----------------
__global__ __launch_bounds__(256, 5) void murenn_all(
        const float* __restrict__ x,
        const float* __restrict__ cw,
        const float* __restrict__ roots,
        const float* __restrict__ beta_p,
        float* __restrict__ out) {
    __shared__ __align__(16) float smem[SMEM_FLOATS];
    const int tid = threadIdx.x;
    const int mt  = blockIdx.x;              // 0..63 (fastest: L3 x-locality)
    const int ch  = blockIdx.y;              // b*C + c
    const int j   = blockIdx.z;              // 0..4
    const float beta = beta_p[0];

    // Interior tiles (mt 1..62): all bounds masks compile out.
    if (mt == 0 || mt == 63)
        run_tile<true >(smem, x, cw, roots, beta, out, j, mt, ch, tid);
    else
        run_tile<false>(smem, x, cw, roots, beta, out, j, mt, ch, tid);
}

// ---------------- launch ----------------
extern "C" void kernel_launch(void* const* d_in, const int* in_sizes, int n_in,
                              void* d_out, int out_size, void* d_ws, size_t ws_size,
                              hipStream_t stream) {
    (void)in_sizes; (void)n_in; (void)out_size; (void)d_ws; (void)ws_size;
    const float* x     = (const float*)d_in[0];
    const float* cw    = (const float*)d_in[1];
    const float* roots = (const float*)d_in[2];
    const float* beta  = (const float*)d_in[3];
    float* out = (float*)d_out;

    dim3 grid(NOUT / M2, NCH, J_);       // (64, 16, 5), mt fastest
    murenn_all<<<grid, 256, 0, stream>>>(x, cw, roots, beta, out);
}

// Round 12
// 161.443 us; speedup vs baseline: 1.9041x; 1.9041x over previous
//
#include <hip/hip_runtime.h>
#include <hip/hip_bf16.h>

typedef float v2f __attribute__((ext_vector_type(2)));

// ---------------- problem constants ----------------
#define B_    4
#define C_    4
#define Q_    8
#define J_    5
#define T_    15
#define NSIG  65536
#define N2SIG 32768
#define NOUT  16384
#define NCH   (B_ * C_)

// ---------------- wavelet filters ----------------
constexpr float H0Oc[13] = {
    -0.00455690456024f, -0.00543947593727f,  0.01702522388155f,  0.02382538479492f,
    -0.10671180468666f,  0.01186609203379f,  0.56881042071212f,  0.75614564389252f,
     0.27529538466888f, -0.11720388769911f, -0.03887280126882f,  0.03466034684485f,
    -0.00388321199915f };
constexpr float H1Oc[13] = {
    -0.00388321199915f, -0.03466034684485f, -0.03887280126882f,  0.11720388769911f,
     0.27529538466888f, -0.75614564389252f,  0.56881042071212f, -0.01186609203379f,
    -0.10671180468666f, -0.02382538479492f,  0.01702522388155f,  0.00543947593727f,
    -0.00455690456024f };
constexpr float H0Ac[10] = {
     0.03516384f, 0.0f, -0.08832942f, 0.23389032f, 0.76027237f,
     0.58751830f, 0.0f, -0.11430184f, 0.0f, 0.0f };
constexpr float H0Bc[10] = {
     0.0f, 0.0f, -0.11430184f, 0.0f, 0.58751830f,
     0.76027237f, 0.23389032f, -0.08832942f, 0.0f, 0.03516384f };
constexpr float H1Ac[10] = {
     0.0f, 0.0f, -0.11430184f, 0.0f, 0.58751830f,
    -0.76027237f, 0.23389032f, 0.08832942f, 0.0f, -0.03516384f };
constexpr float H1Bc[10] = {
    -0.03516384f, 0.0f, 0.08832942f, 0.23389032f, -0.76027237f,
     0.58751830f, 0.0f, -0.11430184f, 0.0f, 0.0f };

// fused two-stage lowpass+decimate: out[m] = sum_n g[n] * u[4m + n - 18]
struct Gtab { float v[37]; };
constexpr Gtab make_g() {
    Gtab g{};
    for (int n = 0; n < 37; ++n) {
        float s = 0.f;
        for (int k = 0; k < 13; ++k) {
            int l = n - 2 * k;
            if (l >= 0 && l < 13) s += H0Oc[k] * H0Oc[l];
        }
        g.v[n] = s;
    }
    return g;
}
constexpr Gtab cG = make_g();

// ---------------- tiling (r10 champion: per-j grid, M2=256) ---------------
// REVERT of r11 (f16-packed U: spill + issue-stall disaster, 260us).
// Standing lessons: r1/r7/r11 U-layout changes all regress (conflicts are
// absorbed; contiguity wins); r3 VGPR cap < ~84 -> spill (watch WRITE_SIZE);
// r5/r6 merged chain -> barrier convoy; r9 chain->ws split net-negative;
// g2 tap-merge blocked by SGPR wall. r10 = 112us top dispatch, the floor:
// ~90% of the LDS-byte ceiling with VALU~55% overlapped.
#define M2    256
#define NUcnt 1057               // 4*(M2-1) + 37
#define NUP   1064               // padded U plane stride (v2f)
#define NBcnt 1169
#define NBP   1176
#define S_    1320               // x window (halo 73 left / 74 right)

#define SMEM_FLOATS (5280 + 2 * NBP)   // 7632 floats = 30528 B

__device__ __forceinline__ v2f zmask(v2f a, bool ok) {
    if (!ok) { a.x = 0.f; a.y = 0.f; }
    return a;
}

// ---------------- post stage (u + fused downsample) ----------------------
// U planes deliberately INTERLEAVED (r1/r7/r11 lessons — do not "fix").
template<int D, bool EDGE>
__device__ __forceinline__ void post_stage(
        const v2f* __restrict__ sRI, v2f* __restrict__ U0, v2f* __restrict__ U1,
        const float* __restrict__ cw, const float* __restrict__ roots,
        float beta, int j, int b, int c, int m0, int mt, int tid,
        float* __restrict__ out) {
    const float lg_is = -0.5f * (float)j;                // log2(inv_scale)
    const float beta2 = beta * exp2f(0.5f * (float)j);   // beta * scale
    const int   u_lo  = 4 * m0 - 18;

    for (int g2 = 0; g2 < 2; ++g2) {
        // uniform weights / alphas (wave-uniform addresses -> SGPRs)
        float w[4][T_], al[4], cq[4];
        #pragma unroll
        for (int qq = 0; qq < 4; ++qq) {
            const int o = c * Q_ + g2 * 4 + qq;
            #pragma unroll
            for (int t = 0; t < T_; t++) w[qq][t] = cw[(size_t)(j * 32 + o) * T_ + t];
            al[qq] = 1.f / (1.f + __expf(-roots[j * 32 + o]));
            cq[qq] = al[qq] * lg_is;
        }

        if constexpr (D == 1) {
            // ---- contiguous-5 u-stage: one 19-v2f window serves 5 items ----
            // 5*256=1280 >= 1057: one group per thread, no grid-stride.
            // Lane stride 5 v2f (40B) -> 16 bank-pairs x 4 lanes = conflict-
            // free; window reads are contiguous (merge-friendly). Same
            // per-item accumulation order as the strided form -> bitwise eq.
            const int i0 = 5 * tid;
            if (i0 < NUcnt) {
                v2f win[19];
                const v2f* tp = sRI + (i0 + 49);   // i + 56 - 7*1
                #pragma unroll
                for (int s = 0; s < 19; ++s) win[s] = tp[s];
                #pragma unroll
                for (int d = 0; d < 5; ++d) {
                    if (i0 + d >= NUcnt) continue;     // only thread 211 trims
                    bool ok = true;
                    if constexpr (EDGE)
                        ok = ((unsigned)(u_lo + i0 + d) < (unsigned)NSIG);
                    float uq[4];
                    #pragma unroll
                    for (int qq = 0; qq < 4; ++qq) {
                        v2f ri; ri.x = 0.f; ri.y = 0.f;
                        #pragma unroll
                        for (int t = 0; t < T_; t++) ri += w[qq][t] * win[d + t];
                        float z2 = fmaf(ri.x, ri.x, ri.y * ri.y);
                        float us = __builtin_amdgcn_sqrtf(z2);
                        float lg = __builtin_amdgcn_logf(us + beta2);
                        float u  = __builtin_amdgcn_exp2f(fmaf(al[qq], lg, cq[qq]));
                        if constexpr (EDGE) uq[qq] = ok ? u : 0.f;
                        else                uq[qq] = u;
                    }
                    v2f p0; p0.x = uq[0]; p0.y = uq[1];
                    v2f p1; p1.x = uq[2]; p1.y = uq[3];
                    U0[i0 + d] = p0; U1[i0 + d] = p1;
                }
            }
        } else {
            // ---- strided u-stage (r2-proven form) for D >= 2 ----
            for (int i = tid; i < NUcnt; i += 256) {
                const v2f* tp = sRI + (i + 56 - 7 * D);
                v2f taps[T_];
                #pragma unroll
                for (int t = 0; t < T_; t++) taps[t] = tp[t * D];
                bool ok = true;
                if constexpr (EDGE) {
                    const int n = u_lo + i;
                    ok = ((unsigned)n < (unsigned)NSIG);
                }
                float uq[4];
                #pragma unroll
                for (int qq = 0; qq < 4; ++qq) {
                    v2f ri; ri.x = 0.f; ri.y = 0.f;
                    #pragma unroll
                    for (int t = 0; t < T_; t++) ri += w[qq][t] * taps[t];
                    float z2 = fmaf(ri.x, ri.x, ri.y * ri.y);
                    float us = __builtin_amdgcn_sqrtf(z2);
                    float lg = __builtin_amdgcn_logf(us + beta2);
                    float u  = __builtin_amdgcn_exp2f(fmaf(al[qq], lg, cq[qq]));
                    if constexpr (EDGE) uq[qq] = ok ? u : 0.f;
                    else                uq[qq] = u;
                }
                v2f p0; p0.x = uq[0]; p0.y = uq[1];
                v2f p1; p1.x = uq[2]; p1.y = uq[3];
                U0[i] = p0; U1[i] = p1;
            }
        }
        __syncthreads();

        // ---- fused 37-tap stride-4 downsample, q-pair packed ----
        {
            const int m = m0 + tid;                 // tid < 256 always
            #pragma unroll
            for (int qp = 0; qp < 2; ++qp) {
                const v2f* up = qp ? U1 : U0;
                const v2f* ub = up + 4 * tid;
                v2f acc; acc.x = 0.f; acc.y = 0.f;
                #pragma unroll
                for (int n = 0; n < 37; ++n) acc += cG.v[n] * ub[n];
                if constexpr (EDGE) {
                    const bool edge = (mt == 0 && tid < 3) || (mt == 63 && tid >= 253);
                    if (edge) {
                        // exact two-stage computation honoring v-plane masking
                        v2f a2; a2.x = 0.f; a2.y = 0.f;
                        for (int k = 0; k < 13; ++k) {
                            int p = 2 * m + k - 6;
                            if (p < 0 || p >= N2SIG) continue;
                            v2f v; v.x = 0.f; v.y = 0.f;
                            for (int l = 0; l < 13; ++l)
                                v += H0Oc[l] * up[4 * tid + 2 * k + l];
                            a2 += H0Oc[k] * v;
                        }
                        acc = a2;
                    }
                }
                const int o = c * Q_ + g2 * 4 + 2 * qp;
                out[((size_t)b * 160 + j * 32 + o)     * NOUT + m] = acc.x;
                out[((size_t)b * 160 + j * 32 + o + 1) * NOUT + m] = acc.y;
            }
        }
        __syncthreads();   // protect U planes before next group's writes
    }
}

// ---------------- whole tile, templated on block-uniform EDGE ------------
template<bool EDGE>
__device__ __forceinline__ void run_tile(
        float* __restrict__ smem,
        const float* __restrict__ x, const float* __restrict__ cw,
        const float* __restrict__ roots, float beta,
        float* __restrict__ out, int j, int mt, int ch, int tid) {
    float* X   = smem;                       // [0,1320)
    float* L1  = smem + S_;                  // [1320,2640)
    v2f*   PP0 = (v2f*)smem;                 // aliases X/L1 (used after dead)
    v2f*   PP1 = (v2f*)(smem + 2 * S_);      // floats [2640,5280)
    v2f*   U0  = (v2f*)smem;                 // aliases PP region (dead then)
    v2f*   U1  = (v2f*)(smem + 2 * NUP);
    v2f*   sRI = (v2f*)(smem + 4 * S_);      // floats [5280,7632)

    const int b   = ch >> 2, c = ch & 3;
    const int m0  = mt * M2;
    const int ofs = 4 * m0 - 147;            // window start (bp index 0 at p=73)
    const float* xc = x + (size_t)ch * NSIG;

    // ---- load x window ----
    for (int p = tid; p < S_; p += 256) {
        if constexpr (EDGE) {
            int g = ofs + p;
            X[p] = ((unsigned)g < (unsigned)NSIG) ? xc[g] : 0.f;
        } else {
            X[p] = xc[ofs + p];
        }
    }
    __syncthreads();

    // ---- UDTCWT chain (branches block-uniform in j) ----
    if (j == 0) {
        for (int i = tid; i < NBcnt; i += 256) {
            int p = 73 + i;
            float a = 0.f;
            #pragma unroll
            for (int k = 0; k < 13; k++) a += H1Oc[k] * X[p + k - 6];
            if constexpr (EDGE) { if ((unsigned)(ofs + p) >= (unsigned)NSIG) a = 0.f; }
            v2f r; r.x = a; r.y = a;
            sRI[i] = r;
        }
    } else {
        // lv0: la1 = conv13(x, H0O) -> L1
        for (int p = 6 + tid; p < 1313; p += 256) {
            float a = 0.f;
            #pragma unroll
            for (int k = 0; k < 13; k++) a += H0Oc[k] * X[p + k - 6];
            if constexpr (EDGE) { if ((unsigned)(ofs + p) >= (unsigned)NSIG) a = 0.f; }
            L1[p] = a;
        }
        __syncthreads();
        if (j == 1) {
            for (int i = tid; i < NBcnt; i += 256) {
                int p = 73 + i;
                v2f r; r.x = 0.f; r.y = 0.f;
                #pragma unroll
                for (int k = 0; k < 10; k++) {
                    v2f hk; hk.x = H1Ac[k]; hk.y = H1Bc[k];
                    r += hk * L1[p + k - 4];
                }
                if constexpr (EDGE) r = zmask(r, (unsigned)(ofs + p) < (unsigned)NSIG);
                sRI[i] = r;
            }
        } else {
            // lv1 (d=1, pad 4): (la2,lb2) -> PP1
            for (int p = 10 + tid; p < 1308; p += 256) {
                v2f a; a.x = 0.f; a.y = 0.f;
                #pragma unroll
                for (int k = 0; k < 10; k++) {
                    v2f hk; hk.x = H0Ac[k]; hk.y = H0Bc[k];
                    a += hk * L1[p + k - 4];
                }
                if constexpr (EDGE) a = zmask(a, (unsigned)(ofs + p) < (unsigned)NSIG);
                PP1[p] = a;
            }
            __syncthreads();
            if (j == 2) {
                for (int i = tid; i < NBcnt; i += 256) {
                    int p = 73 + i;
                    v2f r; r.x = 0.f; r.y = 0.f;
                    #pragma unroll
                    for (int k = 0; k < 10; k++) {
                        v2f hk; hk.x = H1Ac[k]; hk.y = H1Bc[k];
                        r += hk * PP1[p + 2 * k - 9];
                    }
                    if constexpr (EDGE) r = zmask(r, (unsigned)(ofs + p) < (unsigned)NSIG);
                    sRI[i] = r;
                }
            } else {
                // lv2 (d=2, pad 9): (la3,lb3) -> PP0  (X/L1 dead)
                for (int p = 19 + tid; p < 1299; p += 256) {
                    v2f a; a.x = 0.f; a.y = 0.f;
                    #pragma unroll
                    for (int k = 0; k < 10; k++) {
                        v2f hk; hk.x = H0Ac[k]; hk.y = H0Bc[k];
                        a += hk * PP1[p + 2 * k - 9];
                    }
                    if constexpr (EDGE) a = zmask(a, (unsigned)(ofs + p) < (unsigned)NSIG);
                    PP0[p] = a;
                }
                __syncthreads();
                if (j == 3) {
                    for (int i = tid; i < NBcnt; i += 256) {
                        int p = 73 + i;
                        v2f r; r.x = 0.f; r.y = 0.f;
                        #pragma unroll
                        for (int k = 0; k < 10; k++) {
                            v2f hk; hk.x = H1Ac[k]; hk.y = H1Bc[k];
                            r += hk * PP0[p + 4 * k - 18];
                        }
                        if constexpr (EDGE) r = zmask(r, (unsigned)(ofs + p) < (unsigned)NSIG);
                        sRI[i] = r;
                    }
                } else {
                    // lv3 (d=4, pad 18): (la4,lb4) -> PP1 (old PP1 dead)
                    for (int p = 37 + tid; p < 1281; p += 256) {
                        v2f a; a.x = 0.f; a.y = 0.f;
                        #pragma unroll
                        for (int k = 0; k < 10; k++) {
                            v2f hk; hk.x = H0Ac[k]; hk.y = H0Bc[k];
                            a += hk * PP0[p + 4 * k - 18];
                        }
                        if constexpr (EDGE) a = zmask(a, (unsigned)(ofs + p) < (unsigned)NSIG);
                        PP1[p] = a;
                    }
                    __syncthreads();
                    // j == 4 bandpass (d=8, pad 36)
                    for (int i = tid; i < NBcnt; i += 256) {
                        int p = 73 + i;
                        v2f r; r.x = 0.f; r.y = 0.f;
                        #pragma unroll
                        for (int k = 0; k < 10; k++) {
                            v2f hk; hk.x = H1Ac[k]; hk.y = H1Bc[k];
                            r += hk * PP1[p + 8 * k - 36];
                        }
                        if constexpr (EDGE) r = zmask(r, (unsigned)(ofs + p) < (unsigned)NSIG);
                        sRI[i] = r;
                    }
                }
            }
        }
    }
    __syncthreads();
    // PP/X/L1 dead: region becomes U planes.

    if (j == 0)      post_stage<1, EDGE>(sRI, U0, U1, cw, roots, beta, 0, b, c, m0, mt, tid, out);
    else if (j == 1) post_stage<1, EDGE>(sRI, U0, U1, cw, roots, beta, 1, b, c, m0, mt, tid, out);
    else if (j == 2) post_stage<2, EDGE>(sRI, U0, U1, cw, roots, beta, 2, b, c, m0, mt, tid, out);
    else if (j == 3) post_stage<4, EDGE>(sRI, U0, U1, cw, roots, beta, 3, b, c, m0, mt, tid, out);
    else             post_stage<8, EDGE>(sRI, U0, U1, cw, roots, beta, 4, b, c, m0, mt, tid, out);
}

// ---------------- fused kernel ----------------
__global__ __launch_bounds__(256, 5) void murenn_all(
        const float* __restrict__ x,
        const float* __restrict__ cw,
        const float* __restrict__ roots,
        const float* __restrict__ beta_p,
        float* __restrict__ out) {
    __shared__ __align__(16) float smem[SMEM_FLOATS];
    const int tid = threadIdx.x;
    const int mt  = blockIdx.x;              // 0..63 (fastest: L3 x-locality)
    const int ch  = blockIdx.y;              // b*C + c
    const int j   = blockIdx.z;              // 0..4
    const float beta = beta_p[0];

    // Interior tiles (mt 1..62): all bounds masks compile out.
    if (mt == 0 || mt == 63)
        run_tile<true >(smem, x, cw, roots, beta, out, j, mt, ch, tid);
    else
        run_tile<false>(smem, x, cw, roots, beta, out, j, mt, ch, tid);
}

// ---------------- launch ----------------
extern "C" void kernel_launch(void* const* d_in, const int* in_sizes, int n_in,
                              void* d_out, int out_size, void* d_ws, size_t ws_size,
                              hipStream_t stream) {
    (void)in_sizes; (void)n_in; (void)out_size; (void)d_ws; (void)ws_size;
    const float* x     = (const float*)d_in[0];
    const float* cw    = (const float*)d_in[1];
    const float* roots = (const float*)d_in[2];
    const float* beta  = (const float*)d_in[3];
    float* out = (float*)d_out;

    dim3 grid(NOUT / M2, NCH, J_);       // (64, 16, 5), mt fastest
    murenn_all<<<grid, 256, 0, stream>>>(x, cw, roots, beta, out);
}